// Round 1
// baseline (106.919 us; speedup 1.0000x reference)
//
#include <hip/hip_runtime.h>
#include <math.h>

// Problem constants (from reference): V=50257, H=2048, E=1024, L=4
#define LSTM_H 2048
#define LSTM_E 1024
#define LSTM_L 4

__device__ __forceinline__ float sigmoidf_(float x) {
    return 1.0f / (1.0f + __expf(-x));
}

// One block (256 threads = 4 waves) per hidden unit j.
// Wave g (0..3) computes gate row (g*H + j):
//   dot(W_ih[row], x) + dot(W_hh[row], h_in) + b_ih[row] + b_hh[row]
// Thread 0 then applies the LSTM cell update.
template<int INW>
__global__ __launch_bounds__(256)
void lstm_layer_kernel(const float* __restrict__ W_ih,   // [4H, INW]
                       const float* __restrict__ W_hh,   // [4H, H]
                       const float* __restrict__ b_ih,   // [4H]
                       const float* __restrict__ b_hh,   // [4H]
                       const float* __restrict__ xbase,  // [INW] (or emb table if token)
                       const int*   __restrict__ token,  // nullptr, or token index for layer 0
                       const float* __restrict__ h_in,   // [H]
                       const float* __restrict__ c_in,   // [H]
                       float* __restrict__ h_out,        // [H]
                       float* __restrict__ c_out)        // [H]
{
    const int j    = blockIdx.x;            // hidden unit 0..H-1
    const int wave = threadIdx.x >> 6;      // gate index 0..3 (i,f,g,o)
    const int lane = threadIdx.x & 63;

    const float* x = xbase;
    if (token) x += (size_t)(*token) * (size_t)INW;   // embedding row

    const int row = wave * LSTM_H + j;

    const float4* __restrict__ wih4 = (const float4*)(W_ih + (size_t)row * INW);
    const float4* __restrict__ whh4 = (const float4*)(W_hh + (size_t)row * LSTM_H);
    const float4* __restrict__ x4   = (const float4*)x;
    const float4* __restrict__ h4   = (const float4*)h_in;

    float s = 0.0f;

    constexpr int NI = (INW / 4) / 64;   // float4 iters over input vec per lane
    #pragma unroll
    for (int t = 0; t < NI; ++t) {
        const int idx = lane + t * 64;
        float4 w = wih4[idx];
        float4 v = x4[idx];
        s += w.x * v.x + w.y * v.y + w.z * v.z + w.w * v.w;
    }

    constexpr int NH = (LSTM_H / 4) / 64;
    #pragma unroll
    for (int t = 0; t < NH; ++t) {
        const int idx = lane + t * 64;
        float4 w = whh4[idx];
        float4 v = h4[idx];
        s += w.x * v.x + w.y * v.y + w.z * v.z + w.w * v.w;
    }

    // wave (64-lane) reduction
    #pragma unroll
    for (int off = 32; off > 0; off >>= 1)
        s += __shfl_down(s, off, 64);

    __shared__ float gsh[4];
    if (lane == 0)
        gsh[wave] = s + b_ih[row] + b_hh[row];
    __syncthreads();

    if (threadIdx.x == 0) {
        const float gi = gsh[0];
        const float gf = gsh[1];
        const float gg = gsh[2];
        const float go = gsh[3];
        const float i_ = sigmoidf_(gi);
        const float f_ = sigmoidf_(gf);
        const float g_ = tanhf(gg);
        const float o_ = sigmoidf_(go);
        const float c  = f_ * c_in[j] + i_ * g_;
        const float h  = o_ * tanhf(c);
        c_out[j] = c;
        h_out[j] = h;
    }
}

// decoded[r] = dot(fc_W[r], h3) + fc_b[r]; one wave per output row.
__global__ __launch_bounds__(256)
void fc_kernel(const float* __restrict__ fc_W,   // [E, H]
               const float* __restrict__ fc_b,   // [E]
               const float* __restrict__ h,      // [H]
               float* __restrict__ out)          // [E]
{
    const int wave = threadIdx.x >> 6;
    const int lane = threadIdx.x & 63;
    const int r = blockIdx.x * 4 + wave;

    const float4* __restrict__ w4 = (const float4*)(fc_W + (size_t)r * LSTM_H);
    const float4* __restrict__ h4 = (const float4*)h;

    float s = 0.0f;
    constexpr int NH = (LSTM_H / 4) / 64;
    #pragma unroll
    for (int t = 0; t < NH; ++t) {
        const int idx = lane + t * 64;
        float4 w = w4[idx];
        float4 v = h4[idx];
        s += w.x * v.x + w.y * v.y + w.z * v.z + w.w * v.w;
    }

    #pragma unroll
    for (int off = 32; off > 0; off >>= 1)
        s += __shfl_down(s, off, 64);

    if (lane == 0)
        out[r] = s + fc_b[r];
}

extern "C" void kernel_launch(void* const* d_in, const int* in_sizes, int n_in,
                              void* d_out, int out_size, void* d_ws, size_t ws_size,
                              hipStream_t stream) {
    // setup_inputs() order:
    // 0: input (int32 [1]), 1: hidden [L,1,H], 2: cell [L,1,H], 3: emb [V,E],
    // 4: W_ih0 [4H,E], 5: W_ihR [L-1,4H,H], 6: W_hh [L,4H,H],
    // 7: b_ih [L,4H], 8: b_hh [L,4H], 9: fc_W [E,H], 10: fc_b [E]
    const int*   token  = (const int*)d_in[0];
    const float* hidden = (const float*)d_in[1];
    const float* cell   = (const float*)d_in[2];
    const float* emb    = (const float*)d_in[3];
    const float* W_ih0  = (const float*)d_in[4];
    const float* W_ihR  = (const float*)d_in[5];
    const float* W_hh   = (const float*)d_in[6];
    const float* b_ih   = (const float*)d_in[7];
    const float* b_hh   = (const float*)d_in[8];
    const float* fc_W   = (const float*)d_in[9];
    const float* fc_b   = (const float*)d_in[10];

    float* out     = (float*)d_out;
    float* decoded = out;                       // [E]
    float* h_new   = out + LSTM_E;              // [L*H]
    float* c_new   = out + LSTM_E + LSTM_L * LSTM_H;  // [L*H]

    const size_t WIH_STRIDE = (size_t)4 * LSTM_H * LSTM_H;  // per-layer W_ihR / W_hh elems
    const size_t B_STRIDE   = (size_t)4 * LSTM_H;

    // Layer 0: x = emb[token] (width E)
    lstm_layer_kernel<LSTM_E><<<LSTM_H, 256, 0, stream>>>(
        W_ih0, W_hh, b_ih, b_hh,
        emb, token,
        hidden, cell,
        h_new, c_new);

    // Layers 1..3: x = h_new of previous layer (width H)
    for (int l = 1; l < LSTM_L; ++l) {
        lstm_layer_kernel<LSTM_H><<<LSTM_H, 256, 0, stream>>>(
            W_ihR + (size_t)(l - 1) * WIH_STRIDE,
            W_hh  + (size_t)l * WIH_STRIDE,
            b_ih  + (size_t)l * B_STRIDE,
            b_hh  + (size_t)l * B_STRIDE,
            h_new + (size_t)(l - 1) * LSTM_H, nullptr,
            hidden + (size_t)l * LSTM_H,
            cell   + (size_t)l * LSTM_H,
            h_new + (size_t)l * LSTM_H,
            c_new + (size_t)l * LSTM_H);
    }

    // FC: decoded = fc_W @ h3 + fc_b
    fc_kernel<<<LSTM_E / 4, 256, 0, stream>>>(
        fc_W, fc_b, h_new + (size_t)(LSTM_L - 1) * LSTM_H, decoded);
}